// Round 1
// baseline (128.346 us; speedup 1.0000x reference)
//
#include <hip/hip_runtime.h>

#define ECE_BINS 20

// Stage 1: per-block binned accumulation of (conf - correct) into 20 LDS
// slots, flushed with one global atomic per bin per block.
__global__ __launch_bounds__(256) void ece_bin_kernel(
    const float4* __restrict__ conf,
    const int4*   __restrict__ corr,
    float* __restrict__ gbins,
    int n4)
{
    __shared__ float s[ECE_BINS];
    if (threadIdx.x < ECE_BINS) s[threadIdx.x] = 0.0f;
    __syncthreads();

    int idx    = blockIdx.x * blockDim.x + threadIdx.x;
    int stride = gridDim.x * blockDim.x;
    for (int i = idx; i < n4; i += stride) {
        float4 c = conf[i];
        int4   k = corr[i];
        int b;
        b = min(max((int)(c.x * 20.0f), 0), ECE_BINS - 1);
        atomicAdd(&s[b], c.x - (float)k.x);
        b = min(max((int)(c.y * 20.0f), 0), ECE_BINS - 1);
        atomicAdd(&s[b], c.y - (float)k.y);
        b = min(max((int)(c.z * 20.0f), 0), ECE_BINS - 1);
        atomicAdd(&s[b], c.z - (float)k.z);
        b = min(max((int)(c.w * 20.0f), 0), ECE_BINS - 1);
        atomicAdd(&s[b], c.w - (float)k.w);
    }

    __syncthreads();
    if (threadIdx.x < ECE_BINS) {
        atomicAdd(&gbins[threadIdx.x], s[threadIdx.x]);
    }
}

// Stage 2: out = (1/N) * sum_b |gbins[b]|
__global__ void ece_final_kernel(const float* __restrict__ gbins,
                                 float* __restrict__ out,
                                 float invN)
{
    if (threadIdx.x == 0) {
        float sum = 0.0f;
        #pragma unroll
        for (int b = 0; b < ECE_BINS; ++b) sum += fabsf(gbins[b]);
        out[0] = sum * invN;
    }
}

extern "C" void kernel_launch(void* const* d_in, const int* in_sizes, int n_in,
                              void* d_out, int out_size, void* d_ws, size_t ws_size,
                              hipStream_t stream) {
    const float4* conf = (const float4*)d_in[0];
    const int4*   corr = (const int4*)d_in[1];
    float* gbins = (float*)d_ws;
    float* out   = (float*)d_out;

    int n  = in_sizes[0];
    int n4 = n / 4;  // N = 8388608, divisible by 4

    // d_ws is poisoned to 0xAA before every launch — zero the 20 bins.
    hipMemsetAsync(d_ws, 0, ECE_BINS * sizeof(float), stream);

    // 1024 blocks (4/CU) x 256 threads: 16 waves/CU, each thread does
    // n4/262144 = 8 float4 iterations — enough in-flight loads for HBM BW.
    ece_bin_kernel<<<1024, 256, 0, stream>>>(conf, corr, gbins, n4);

    ece_final_kernel<<<1, 64, 0, stream>>>(gbins, out, 1.0f / (float)n);
}

// Round 2
// 127.278 us; speedup vs baseline: 1.0084x; 1.0084x over previous
//
#include <hip/hip_runtime.h>

#define ECE_BINS 20
#define COLS 64          // one column per lane -> no intra-wave same-address atomics
#define P1_BLOCK 256
#define P1_GRID_MAX 2048

// Pass 1: grid-stride accumulate (conf - correct) into per-lane-replicated LDS
// bins, block-reduce, write 20 partials per block (no global atomics, no init).
__global__ __launch_bounds__(P1_BLOCK) void ece_pass1(
    const float4* __restrict__ conf,
    const int4*   __restrict__ corr,
    float* __restrict__ partials,   // [gridDim.x][ECE_BINS]
    int n4)
{
    __shared__ float s[ECE_BINS * COLS];
    __shared__ float s2[ECE_BINS * 8];

    const int tid  = threadIdx.x;
    const int lane = tid & 63;

    for (int i = tid; i < ECE_BINS * COLS; i += P1_BLOCK) s[i] = 0.0f;
    __syncthreads();

    const int idx    = blockIdx.x * P1_BLOCK + tid;
    const int stride = gridDim.x * P1_BLOCK;
    for (int i = idx; i < n4; i += stride) {
        float4 c = conf[i];
        int4   k = corr[i];
        int b;
        b = min((int)(c.x * 20.0f), ECE_BINS - 1);
        atomicAdd(&s[b * COLS + lane], c.x - (float)k.x);
        b = min((int)(c.y * 20.0f), ECE_BINS - 1);
        atomicAdd(&s[b * COLS + lane], c.y - (float)k.y);
        b = min((int)(c.z * 20.0f), ECE_BINS - 1);
        atomicAdd(&s[b * COLS + lane], c.z - (float)k.z);
        b = min((int)(c.w * 20.0f), ECE_BINS - 1);
        atomicAdd(&s[b * COLS + lane], c.w - (float)k.w);
    }
    __syncthreads();

    // reduce 64 cols -> 8 segments of 8
    if (tid < ECE_BINS * 8) {
        int b = tid >> 3, seg = tid & 7;
        float a = 0.0f;
        #pragma unroll
        for (int j = 0; j < 8; ++j) a += s[b * COLS + seg * 8 + j];
        s2[tid] = a;
    }
    __syncthreads();

    // 8 -> 1, store per-block partial
    if (tid < ECE_BINS) {
        float a = 0.0f;
        #pragma unroll
        for (int j = 0; j < 8; ++j) a += s2[tid * 8 + j];
        partials[blockIdx.x * ECE_BINS + tid] = a;
    }
}

// Pass 2: reduce [nb][20] partials -> out = (1/N) * sum_b |bin_b|
__global__ __launch_bounds__(256) void ece_pass2(
    const float4* __restrict__ partials,  // rows of 20 floats = 5 x float4
    float* __restrict__ out,
    int nb, float invN)
{
    __shared__ float s[ECE_BINS * 256];
    __shared__ float s2[ECE_BINS * 8];
    __shared__ float s3[ECE_BINS];

    const int tid = threadIdx.x;
    float acc[ECE_BINS];
    #pragma unroll
    for (int b = 0; b < ECE_BINS; ++b) acc[b] = 0.0f;

    for (int row = tid; row < nb; row += 256) {
        const float4* r = partials + row * 5;
        #pragma unroll
        for (int q = 0; q < 5; ++q) {
            float4 v = r[q];
            acc[q * 4 + 0] += v.x;
            acc[q * 4 + 1] += v.y;
            acc[q * 4 + 2] += v.z;
            acc[q * 4 + 3] += v.w;
        }
    }
    #pragma unroll
    for (int b = 0; b < ECE_BINS; ++b) s[b * 256 + tid] = acc[b];
    __syncthreads();

    if (tid < ECE_BINS * 8) {
        int b = tid >> 3, seg = tid & 7;
        float a = 0.0f;
        #pragma unroll
        for (int j = 0; j < 32; ++j) a += s[b * 256 + seg * 32 + j];
        s2[tid] = a;
    }
    __syncthreads();
    if (tid < ECE_BINS) {
        float a = 0.0f;
        #pragma unroll
        for (int j = 0; j < 8; ++j) a += s2[tid * 8 + j];
        s3[tid] = fabsf(a);
    }
    __syncthreads();
    if (tid == 0) {
        float sum = 0.0f;
        #pragma unroll
        for (int b = 0; b < ECE_BINS; ++b) sum += s3[b];
        out[0] = sum * invN;
    }
}

extern "C" void kernel_launch(void* const* d_in, const int* in_sizes, int n_in,
                              void* d_out, int out_size, void* d_ws, size_t ws_size,
                              hipStream_t stream) {
    const float4* conf = (const float4*)d_in[0];
    const int4*   corr = (const int4*)d_in[1];
    float* partials = (float*)d_ws;
    float* out      = (float*)d_out;

    int n  = in_sizes[0];
    int n4 = n / 4;  // N = 8388608, divisible by 4

    // Cap grid by workspace capacity (20 floats = 80 B per block).
    int grid = P1_GRID_MAX;
    size_t cap = ws_size / (ECE_BINS * sizeof(float));
    if ((size_t)grid > cap) grid = (int)cap;
    if (grid < 1) grid = 1;

    ece_pass1<<<grid, P1_BLOCK, 0, stream>>>(conf, corr, partials, n4);
    ece_pass2<<<1, 256, 0, stream>>>((const float4*)partials, out, grid, 1.0f / (float)n);
}

// Round 3
// 99.096 us; speedup vs baseline: 1.2952x; 1.2844x over previous
//
#include <hip/hip_runtime.h>

#define ECE_BINS 20
#define P1_BLOCK 256
#define P1_GRID  2048

// Pass 1: per-thread register accumulators (NO LDS atomics — LDS atomicAdd
// measured ~190 cyc/wave-instr, lane-serialized; it was the R1/R2 bottleneck).
// Branchless 20-way select per element, plain ds_write block-reduce at end.
__global__ __launch_bounds__(P1_BLOCK) void ece_pass1(
    const float4* __restrict__ conf,
    const int4*   __restrict__ corr,
    float* __restrict__ partials,   // [gridDim.x][ECE_BINS]
    int n4)
{
    const int tid = threadIdx.x;

    float acc[ECE_BINS];
    #pragma unroll
    for (int b = 0; b < ECE_BINS; ++b) acc[b] = 0.0f;

    const int idx    = blockIdx.x * P1_BLOCK + tid;
    const int stride = gridDim.x * P1_BLOCK;

    #pragma unroll 2
    for (int i = idx; i < n4; i += stride) {
        float4 c = conf[i];
        int4   k = corr[i];
        float d0 = c.x - (float)k.x; int b0 = min((int)(c.x * 20.0f), ECE_BINS - 1);
        float d1 = c.y - (float)k.y; int b1 = min((int)(c.y * 20.0f), ECE_BINS - 1);
        float d2 = c.z - (float)k.z; int b2 = min((int)(c.z * 20.0f), ECE_BINS - 1);
        float d3 = c.w - (float)k.w; int b3 = min((int)(c.w * 20.0f), ECE_BINS - 1);
        #pragma unroll
        for (int t = 0; t < ECE_BINS; ++t) {
            acc[t] += (b0 == t) ? d0 : 0.0f;
            acc[t] += (b1 == t) ? d1 : 0.0f;
            acc[t] += (b2 == t) ? d2 : 0.0f;
            acc[t] += (b3 == t) ? d3 : 0.0f;
        }
    }

    // Block reduce: plain LDS writes (parallel 32-bank path), tree-reduce.
    __shared__ float s[ECE_BINS * P1_BLOCK];   // 20 KB -> 8 blocks/CU OK
    __shared__ float s2[ECE_BINS * 8];

    #pragma unroll
    for (int b = 0; b < ECE_BINS; ++b) s[b * P1_BLOCK + tid] = acc[b];
    __syncthreads();

    if (tid < ECE_BINS * 8) {
        int b = tid >> 3, seg = tid & 7;
        float a = 0.0f;
        #pragma unroll
        for (int j = 0; j < 32; ++j) a += s[b * P1_BLOCK + seg * 32 + j];
        s2[tid] = a;
    }
    __syncthreads();

    if (tid < ECE_BINS) {
        float a = 0.0f;
        #pragma unroll
        for (int j = 0; j < 8; ++j) a += s2[tid * 8 + j];
        partials[blockIdx.x * ECE_BINS + tid] = a;
    }
}

// Pass 2: reduce [nb][20] partials -> out = (1/N) * sum_b |bin_b|
__global__ __launch_bounds__(256) void ece_pass2(
    const float4* __restrict__ partials,  // rows of 20 floats = 5 x float4
    float* __restrict__ out,
    int nb, float invN)
{
    __shared__ float s[ECE_BINS * 256];
    __shared__ float s2[ECE_BINS * 8];
    __shared__ float s3[ECE_BINS];

    const int tid = threadIdx.x;
    float acc[ECE_BINS];
    #pragma unroll
    for (int b = 0; b < ECE_BINS; ++b) acc[b] = 0.0f;

    for (int row = tid; row < nb; row += 256) {
        const float4* r = partials + row * 5;
        #pragma unroll
        for (int q = 0; q < 5; ++q) {
            float4 v = r[q];
            acc[q * 4 + 0] += v.x;
            acc[q * 4 + 1] += v.y;
            acc[q * 4 + 2] += v.z;
            acc[q * 4 + 3] += v.w;
        }
    }
    #pragma unroll
    for (int b = 0; b < ECE_BINS; ++b) s[b * 256 + tid] = acc[b];
    __syncthreads();

    if (tid < ECE_BINS * 8) {
        int b = tid >> 3, seg = tid & 7;
        float a = 0.0f;
        #pragma unroll
        for (int j = 0; j < 32; ++j) a += s[b * 256 + seg * 32 + j];
        s2[tid] = a;
    }
    __syncthreads();
    if (tid < ECE_BINS) {
        float a = 0.0f;
        #pragma unroll
        for (int j = 0; j < 8; ++j) a += s2[tid * 8 + j];
        s3[tid] = fabsf(a);
    }
    __syncthreads();
    if (tid == 0) {
        float sum = 0.0f;
        #pragma unroll
        for (int b = 0; b < ECE_BINS; ++b) sum += s3[b];
        out[0] = sum * invN;
    }
}

extern "C" void kernel_launch(void* const* d_in, const int* in_sizes, int n_in,
                              void* d_out, int out_size, void* d_ws, size_t ws_size,
                              hipStream_t stream) {
    const float4* conf = (const float4*)d_in[0];
    const int4*   corr = (const int4*)d_in[1];
    float* partials = (float*)d_ws;
    float* out      = (float*)d_out;

    int n  = in_sizes[0];
    int n4 = n / 4;  // N = 8388608, divisible by 4

    int grid = P1_GRID;
    size_t cap = ws_size / (ECE_BINS * sizeof(float));
    if ((size_t)grid > cap) grid = (int)cap;
    if (grid < 1) grid = 1;

    ece_pass1<<<grid, P1_BLOCK, 0, stream>>>(conf, corr, partials, n4);
    ece_pass2<<<1, 256, 0, stream>>>((const float4*)partials, out, grid, 1.0f / (float)n);
}

// Round 4
// 96.915 us; speedup vs baseline: 1.3243x; 1.0225x over previous
//
#include <hip/hip_runtime.h>

#define ECE_BINS 20
#define P1_BLOCK 256
#define P1_GRID  2048

// Pass 1: per-thread PRIVATE LDS bin columns, non-atomic read-modify-write.
// Layout s[b*256 + tid]: bank = (b*256+tid)%32 = tid%32 -> conflict-free for
// ANY data-dependent bin; column is thread-private -> no atomics.
// (R2 showed LDS atomics lane-serialize ~190cyc; R3's 20-way VGPR select fixed
// that but costs ~66 VALU/elem; this is ~7 VALU + 2 LDS ops per element.)
__global__ __launch_bounds__(P1_BLOCK) void ece_pass1(
    const float4* __restrict__ conf,
    const int4*   __restrict__ corr,
    float* __restrict__ partials,   // [gridDim.x][ECE_BINS]
    int n4)
{
    __shared__ float s[ECE_BINS * P1_BLOCK];   // 20 KB -> 8 blocks/CU
    __shared__ float s2[ECE_BINS * 8];

    const int tid = threadIdx.x;

    // zero own column only — no barrier needed before use (thread-private)
    #pragma unroll
    for (int b = 0; b < ECE_BINS; ++b) s[b * P1_BLOCK + tid] = 0.0f;

    const int idx    = blockIdx.x * P1_BLOCK + tid;
    const int stride = gridDim.x * P1_BLOCK;

    for (int i = idx; i < n4; i += stride) {
        float4 c = conf[i];
        int4   k = corr[i];
        int b0 = min((int)(c.x * 20.0f), ECE_BINS - 1);
        s[b0 * P1_BLOCK + tid] += c.x - (float)k.x;
        int b1 = min((int)(c.y * 20.0f), ECE_BINS - 1);
        s[b1 * P1_BLOCK + tid] += c.y - (float)k.y;
        int b2 = min((int)(c.z * 20.0f), ECE_BINS - 1);
        s[b2 * P1_BLOCK + tid] += c.z - (float)k.z;
        int b3 = min((int)(c.w * 20.0f), ECE_BINS - 1);
        s[b3 * P1_BLOCK + tid] += c.w - (float)k.w;
    }
    __syncthreads();

    // tree-reduce the 256 columns per bin
    if (tid < ECE_BINS * 8) {
        int b = tid >> 3, seg = tid & 7;
        float a = 0.0f;
        #pragma unroll
        for (int j = 0; j < 32; ++j) a += s[b * P1_BLOCK + seg * 32 + j];
        s2[tid] = a;
    }
    __syncthreads();

    if (tid < ECE_BINS) {
        float a = 0.0f;
        #pragma unroll
        for (int j = 0; j < 8; ++j) a += s2[tid * 8 + j];
        partials[blockIdx.x * ECE_BINS + tid] = a;
    }
}

// Pass 2: reduce [nb][20] partials -> out = (1/N) * sum_b |bin_b|
__global__ __launch_bounds__(256) void ece_pass2(
    const float4* __restrict__ partials,  // rows of 20 floats = 5 x float4
    float* __restrict__ out,
    int nb, float invN)
{
    __shared__ float s[ECE_BINS * 256];
    __shared__ float s2[ECE_BINS * 8];
    __shared__ float s3[ECE_BINS];

    const int tid = threadIdx.x;
    float acc[ECE_BINS];
    #pragma unroll
    for (int b = 0; b < ECE_BINS; ++b) acc[b] = 0.0f;

    for (int row = tid; row < nb; row += 256) {
        const float4* r = partials + row * 5;
        #pragma unroll
        for (int q = 0; q < 5; ++q) {
            float4 v = r[q];
            acc[q * 4 + 0] += v.x;
            acc[q * 4 + 1] += v.y;
            acc[q * 4 + 2] += v.z;
            acc[q * 4 + 3] += v.w;
        }
    }
    #pragma unroll
    for (int b = 0; b < ECE_BINS; ++b) s[b * 256 + tid] = acc[b];
    __syncthreads();

    if (tid < ECE_BINS * 8) {
        int b = tid >> 3, seg = tid & 7;
        float a = 0.0f;
        #pragma unroll
        for (int j = 0; j < 32; ++j) a += s[b * 256 + seg * 32 + j];
        s2[tid] = a;
    }
    __syncthreads();
    if (tid < ECE_BINS) {
        float a = 0.0f;
        #pragma unroll
        for (int j = 0; j < 8; ++j) a += s2[tid * 8 + j];
        s3[tid] = fabsf(a);
    }
    __syncthreads();
    if (tid == 0) {
        float sum = 0.0f;
        #pragma unroll
        for (int b = 0; b < ECE_BINS; ++b) sum += s3[b];
        out[0] = sum * invN;
    }
}

extern "C" void kernel_launch(void* const* d_in, const int* in_sizes, int n_in,
                              void* d_out, int out_size, void* d_ws, size_t ws_size,
                              hipStream_t stream) {
    const float4* conf = (const float4*)d_in[0];
    const int4*   corr = (const int4*)d_in[1];
    float* partials = (float*)d_ws;
    float* out      = (float*)d_out;

    int n  = in_sizes[0];
    int n4 = n / 4;  // N = 8388608, divisible by 4

    int grid = P1_GRID;
    size_t cap = ws_size / (ECE_BINS * sizeof(float));
    if ((size_t)grid > cap) grid = (int)cap;
    if (grid < 1) grid = 1;

    ece_pass1<<<grid, P1_BLOCK, 0, stream>>>(conf, corr, partials, n4);
    ece_pass2<<<1, 256, 0, stream>>>((const float4*)partials, out, grid, 1.0f / (float)n);
}